// Round 9
// baseline (1442.306 us; speedup 1.0000x reference)
//
#include <hip/hip_runtime.h>
#include <hip/hip_bf16.h>
#include <math.h>

// Problem constants
#define NSEQ 2048
#define TT   128
#define EE   128
#define HH   256
#define GG   1024
#define LL   1000
#define NT   512        // 8 waves
#define NGRP 32         // groups of 64 seqs
#define NMEM 8          // members (blocks) per group; member owns 32 h-units
#define SEQG 64
#define NKT  12         // K-tiles of 32: 4 x + 8 h
#define NMT  64
#define NKT_O 8
#define WSA_ELEMS (NMT * NKT * 64 * 8)      // 768 KB bf16
#define WSO_ELEMS (NMT * NKT_O * 64 * 8)    // 512 KB bf16
// ghf: [grp][member][parity][cg][64 lanes][8 shorts] = 2 MB
#define GHF_SHORTS ((size_t)NGRP * NMEM * 2 * 4 * 64 * 8)
#define NFLAGS (NGRP * NMEM * 4 * 2)        // per (grp, member, cg, jj)

typedef __attribute__((ext_vector_type(8))) short bf16x8;
typedef __attribute__((ext_vector_type(4))) float f32x4;
typedef unsigned long long u64;

__device__ __forceinline__ unsigned short f2bf(float f) {
    union { float f; unsigned u; } v; v.f = f;
    unsigned r = v.u + 0x7FFF + ((v.u >> 16) & 1);   // RNE
    return (unsigned short)(r >> 16);
}
__device__ __forceinline__ float sigf(float x) { return 1.0f / (1.0f + __expf(-x)); }
__device__ __forceinline__ float tanh_fast(float x) { return 1.0f - 2.0f / (1.0f + __expf(2.0f * x)); }

// system-scope relaxed 8B ops: sc0+sc1 (served at coherence point) — NO wbl2/inv
__device__ __forceinline__ void st8_sys(unsigned short* p, unsigned lo, unsigned hi) {
    u64 v = (u64)lo | ((u64)hi << 32);
    __hip_atomic_store((u64*)p, v, __ATOMIC_RELAXED, __HIP_MEMORY_SCOPE_SYSTEM);
}
__device__ __forceinline__ bf16x8 ld16_sys(const unsigned short* p) {
    u64 lo = __hip_atomic_load((const u64*)p,       __ATOMIC_RELAXED, __HIP_MEMORY_SCOPE_SYSTEM);
    u64 hi = __hip_atomic_load((const u64*)(p + 4), __ATOMIC_RELAXED, __HIP_MEMORY_SCOPE_SYSTEM);
    union { u64 q[2]; bf16x8 v; } u; u.q[0] = lo; u.q[1] = hi;
    return u.v;
}

__global__ void init_out_kernel(float* out, int* flags) {
    int i = blockIdx.x * blockDim.x + threadIdx.x;
    if (i < HH + 1) out[i] = 0.0f;
    if (i < NFLAGS) flags[i] = 0;
}

// Pre-shuffle weights into MFMA A-fragment order, bf16 (layout verified R2-R8).
__global__ void convert_weights(const float* __restrict__ Wih, const float* __restrict__ Whh,
                                const float* __restrict__ Wout,
                                unsigned short* __restrict__ wsA, unsigned short* __restrict__ wsO) {
    int gid = blockIdx.x * blockDim.x + threadIdx.x;
    if (gid < NMT * NKT * 64) {
        int lane = gid & 63, tile = gid >> 6;
        int kt = tile % NKT, mt = tile / NKT;
        int row = mt * 16 + (lane & 15);
        int kb  = kt * 32 + (lane >> 4) * 8;
        unsigned short o[8];
#pragma unroll
        for (int j = 0; j < 8; ++j) {
            int k = kb + j;
            float v = (k < EE) ? Wih[row * EE + k] : Whh[row * HH + (k - EE)];
            o[j] = f2bf(v);
        }
        uint4 pk;
        pk.x = o[0] | ((unsigned)o[1] << 16); pk.y = o[2] | ((unsigned)o[3] << 16);
        pk.z = o[4] | ((unsigned)o[5] << 16); pk.w = o[6] | ((unsigned)o[7] << 16);
        *(uint4*)(wsA + (size_t)gid * 8) = pk;
    } else {
        int g2 = gid - NMT * NKT * 64;
        if (g2 < NMT * NKT_O * 64) {
            int lane = g2 & 63, tile = g2 >> 6;
            int kt = tile % NKT_O, mt = tile / NKT_O;
            int row = mt * 16 + (lane & 15);
            int ub  = kt * 32 + (lane >> 4) * 8;
            unsigned short o[8];
#pragma unroll
            for (int j = 0; j < 8; ++j)
                o[j] = (row < LL) ? f2bf(Wout[row * HH + ub + j]) : (unsigned short)0;
            uint4 pk;
            pk.x = o[0] | ((unsigned)o[1] << 16); pk.y = o[2] | ((unsigned)o[3] << 16);
            pk.z = o[4] | ((unsigned)o[5] << 16); pk.w = o[6] | ((unsigned)o[7] << 16);
            *(uint4*)(wsO + (size_t)g2 * 8) = pk;
        }
    }
}

// Barrier-free 8-way split LSTM: per-wave flags (member,cg,jj). The K-loop has
// ZERO __syncthreads; each wave self-syncs on 16 flags of its own cg.
// x B-frags gathered directly into registers; h exchanged via L3 (sc0sc1).
__launch_bounds__(NT, 2)
__global__ void lstm_wave_kernel(
    const int* __restrict__ tokens, const int* __restrict__ lengths,
    const int* __restrict__ labels, const float* __restrict__ emb,
    const float* __restrict__ bih,  const float* __restrict__ bhh,
    const float* __restrict__ bout,
    const unsigned short* __restrict__ wsA, const unsigned short* __restrict__ wsO,
    unsigned short* __restrict__ ghf, int* __restrict__ flags,
    float* __restrict__ out)
{
    __shared__ __align__(16) unsigned short wlds[8 * 12 * 64 * 8];   // 96 KB A-frags
    __shared__ int labv[SEQG];

    const int tid = threadIdx.x;
    const int w   = tid >> 6;
    const int l   = tid & 63;
    const int lq  = l >> 4;
    const int ls  = l & 15;
    const int jj  = w >> 2;        // row half (0/1)
    const int cg  = w & 3;         // col group (16 seqs)
    const int grp = blockIdx.x & (NGRP - 1);
    const int m   = blockIdx.x >> 5;     // same XCD for all members under %8
    const int n0  = grp * SEQG;

    int* const flagBase = flags + grp * (NMEM * 8);   // 64 flags per group

    int maxlen = lengths[n0 + l];
#pragma unroll
    for (int s = 1; s < 64; s <<= 1) maxlen = max(maxlen, __shfl_xor(maxlen, s, 64));
    const int len_s = lengths[n0 + cg * 16 + ls];
    const int myseq = n0 + cg * 16 + ls;     // seq for x gather (col ls of cg)

    if (tid < SEQG) labv[tid] = labels[n0 + tid];

    // biases in registers
    f32x4 biasv[4];
#pragma unroll
    for (int g = 0; g < 4; ++g)
#pragma unroll
        for (int r = 0; r < 4; ++r) {
            int row = 256 * g + 32 * m + 16 * jj + 4 * lq + r;
            biasv[g][r] = bih[row] + bhh[row];
        }

    // ---- one-time: this member's A-frags (8 mt x 12 kt) -> LDS ----
    for (int idx = tid; idx < 8 * 12 * 64; idx += NT) {
        int mtl = idx / 768;
        int rem = idx - mtl * 768;
        int kt = rem >> 6, l2 = rem & 63;
        int g = mtl >> 1, j2 = mtl & 1;
        int gmt = 16 * g + 2 * m + j2;
        *(uint4*)&wlds[(size_t)idx * 8] =
            *(const uint4*)(wsA + ((size_t)(gmt * NKT + kt) * 64 + l2) * 8);
    }

    // h publish mapping: unit u = 16*jj + 4*lq + r; this wave writes 512B of its
    // member's cg tile (disjoint from the jj-partner wave).
    const int u8      = 2 * jj + (lq >> 1);
    const int lanep_h = 16 * u8 + ls;
    const int joff_h  = 4 * (lq & 1);
    const size_t gb0  = ((size_t)((grp * NMEM + m) * 2 + 0) * 4 + cg) * 512 + (size_t)lanep_h * 8 + joff_h;
    const size_t gb1  = gb0 + 4 * 512;
    const int myFlag  = m * 8 + cg * 2 + jj;

    // zero own parity-0 slots (h(0) = 0)
    st8_sys(&ghf[gb0], 0, 0);

    // x gather: lane l needs emb[token(myseq,t)][kt*32 + (l>>4)*8 + j], j=0..7
    const int xoff = (l >> 4) * 8;
    bf16x8 bx[4];
    {
        int tok = tokens[myseq * TT + 0];
        const float* er = emb + (size_t)tok * EE + xoff;
#pragma unroll
        for (int kt = 0; kt < 4; ++kt) {
            f32x4 a = *(const f32x4*)(er + kt * 32);
            f32x4 b = *(const f32x4*)(er + kt * 32 + 4);
            union { unsigned u[4]; bf16x8 v; } pk;
            pk.u[0] = f2bf(a[0]) | ((unsigned)f2bf(a[1]) << 16);
            pk.u[1] = f2bf(a[2]) | ((unsigned)f2bf(a[3]) << 16);
            pk.u[2] = f2bf(b[0]) | ((unsigned)f2bf(b[1]) << 16);
            pk.u[3] = f2bf(b[2]) | ((unsigned)f2bf(b[3]) << 16);
            bx[kt] = pk.v;
        }
    }

    __syncthreads();   // ONLY block barrier: wlds visible (also after labv)

    // wave-local drain of the zero-store, then post flag = 1 (h(0) published)
    __builtin_amdgcn_s_waitcnt(0);
    asm volatile("" ::: "memory");
    if (l == 0)
        __hip_atomic_store(&flagBase[myFlag], 1, __ATOMIC_RELAXED, __HIP_MEMORY_SCOPE_SYSTEM);

    // acc = bias + W_ih * x(0)
    f32x4 acc[4];
#pragma unroll
    for (int g = 0; g < 4; ++g) acc[g] = biasv[g];
#pragma unroll
    for (int kt = 0; kt < 4; ++kt)
#pragma unroll
        for (int g = 0; g < 4; ++g)
            acc[g] = __builtin_amdgcn_mfma_f32_16x16x32_bf16(
                *(const bf16x8*)&wlds[(size_t)(((2 * g + jj) * 12 + kt) * 64 + l) * 8],
                bx[kt], acc[g], 0, 0, 0);

    float c_reg[4], h_reg[4];
#pragma unroll
    for (int r = 0; r < 4; ++r) { c_reg[r] = 0.0f; h_reg[r] = 0.0f; }

    // per-wave wait: 16 flags (8 members x 2 jj) of this cg >= need
    auto wave_wait = [&](int need) {
        int f;
        do {
            f = 0x7fffffff;
            if (l < 16)
                f = __hip_atomic_load(&flagBase[(l >> 1) * 8 + cg * 2 + (l & 1)],
                                      __ATOMIC_RELAXED, __HIP_MEMORY_SCOPE_SYSTEM);
            f = min(f, __shfl_xor(f, 1, 64));
            f = min(f, __shfl_xor(f, 2, 64));
            f = min(f, __shfl_xor(f, 4, 64));
            f = min(f, __shfl_xor(f, 8, 64));
            f = __shfl(f, 0, 64);
        } while (f < need);
    };

    // ---- recurrence: zero barriers ----
    for (int t = 0; t < maxlen; ++t) {
        const int par = t & 1;

        // wait for all members' h(t) of this cg
        wave_wait(t + 1);

        // 8 member tiles (incl own) as B-frags from L3
        bf16x8 bp[8];
#pragma unroll
        for (int p = 0; p < 8; ++p) {
            size_t b = ((size_t)((grp * NMEM + p) * 2 + par) * 4 + cg) * 512;
            bp[p] = ld16_sys(&ghf[b + (size_t)l * 8]);
        }
        // h-part MFMAs (A from LDS, static)
#pragma unroll
        for (int p = 0; p < 8; ++p)
#pragma unroll
            for (int g = 0; g < 4; ++g)
                acc[g] = __builtin_amdgcn_mfma_f32_16x16x32_bf16(
                    *(const bf16x8*)&wlds[(size_t)(((2 * g + jj) * 12 + 4 + p) * 64 + l) * 8],
                    bp[p], acc[g], 0, 0, 0);

        // in-register cell update
        const bool live = (t < len_s);
#pragma unroll
        for (int r = 0; r < 4; ++r) {
            if (live) {
                float ig = sigf(acc[0][r]);
                float fg = sigf(acc[1][r]);
                float gg = tanh_fast(acc[2][r]);
                float og = sigf(acc[3][r]);
                float cc = fg * c_reg[r] + ig * gg;
                c_reg[r] = cc;
                h_reg[r] = og * tanh_fast(cc);
            }
        }

        // publish h(t+1) to parity par^1; wave-local drain; post flag t+2
        {
            uint2 hp;
            hp.x = f2bf(h_reg[0]) | ((unsigned)f2bf(h_reg[1]) << 16);
            hp.y = f2bf(h_reg[2]) | ((unsigned)f2bf(h_reg[3]) << 16);
            st8_sys(&ghf[par ? gb0 : gb1], hp.x, hp.y);
        }
        __builtin_amdgcn_s_waitcnt(0);
        asm volatile("" ::: "memory");
        if (l == 0)
            __hip_atomic_store(&flagBase[myFlag], t + 2, __ATOMIC_RELAXED, __HIP_MEMORY_SCOPE_SYSTEM);

        // off critical path: gather+pack x(t+1), pre-accumulate x-part for t+1
        if (t + 1 < maxlen) {
            int tok = tokens[myseq * TT + t + 1];
            const float* er = emb + (size_t)tok * EE + xoff;
#pragma unroll
            for (int kt = 0; kt < 4; ++kt) {
                f32x4 a = *(const f32x4*)(er + kt * 32);
                f32x4 b = *(const f32x4*)(er + kt * 32 + 4);
                union { unsigned u[4]; bf16x8 v; } pk;
                pk.u[0] = f2bf(a[0]) | ((unsigned)f2bf(a[1]) << 16);
                pk.u[1] = f2bf(a[2]) | ((unsigned)f2bf(a[3]) << 16);
                pk.u[2] = f2bf(b[0]) | ((unsigned)f2bf(b[1]) << 16);
                pk.u[3] = f2bf(b[2]) | ((unsigned)f2bf(b[3]) << 16);
                bx[kt] = pk.v;
            }
#pragma unroll
            for (int g = 0; g < 4; ++g) acc[g] = biasv[g];
#pragma unroll
            for (int kt = 0; kt < 4; ++kt)
#pragma unroll
                for (int g = 0; g < 4; ++g)
                    acc[g] = __builtin_amdgcn_mfma_f32_16x16x32_bf16(
                        *(const bf16x8*)&wlds[(size_t)(((2 * g + jj) * 12 + kt) * 64 + l) * 8],
                        bx[kt], acc[g], 0, 0, 0);
        }
    }

    // ---- epilogue 1: embeds = mean(c_f) for own 32 units ----
#pragma unroll
    for (int r = 0; r < 4; ++r) {
        float v = c_reg[r];
        v += __shfl_xor(v, 1, 64);
        v += __shfl_xor(v, 2, 64);
        v += __shfl_xor(v, 4, 64);
        v += __shfl_xor(v, 8, 64);
        if (ls == 0)
            atomicAdd(&out[32 * m + 16 * jj + 4 * lq + r], v * (1.0f / NSEQ));
    }

    // ---- epilogue 2 (member 0): logits GEMM + log-softmax ----
    if (m == 0) {
        // wait all 64 flags >= maxlen+1 (every wave published final h)
        {
            int f;
            do {
                f = __hip_atomic_load(&flagBase[l], __ATOMIC_RELAXED, __HIP_MEMORY_SCOPE_SYSTEM);
                f = min(f, __shfl_xor(f, 1, 64));
                f = min(f, __shfl_xor(f, 2, 64));
                f = min(f, __shfl_xor(f, 4, 64));
                f = min(f, __shfl_xor(f, 8, 64));
                f = min(f, __shfl_xor(f, 16, 64));
                f = min(f, __shfl_xor(f, 32, 64));
            } while (f < maxlen + 1);
        }
        const int fin = maxlen & 1;
        float* lg = (float*)wlds;            // reuse: 16 seqs x 1024 logits (64 KB)
        float lossAcc = 0.0f;

        for (int cgo = 0; cgo < 4; ++cgo) {
            bf16x8 bq[8];
#pragma unroll
            for (int p = 0; p < 8; ++p) {
                size_t b = ((size_t)((grp * NMEM + p) * 2 + fin) * 4 + cgo) * 512;
                bq[p] = ld16_sys(&ghf[b + (size_t)l * 8]);
            }
            __syncthreads();   // prev cgo softmax reads of lg done; wlds reads done
#pragma unroll
            for (int i = 0; i < 8; ++i) {
                int mt = 8 * w + i;
                f32x4 a = {0.0f, 0.0f, 0.0f, 0.0f};
#pragma unroll
                for (int p = 0; p < 8; ++p)
                    a = __builtin_amdgcn_mfma_f32_16x16x32_bf16(
                        *(const bf16x8*)(wsO + ((size_t)(mt * NKT_O + p) * 64 + l) * 8),
                        bq[p], a, 0, 0, 0);
#pragma unroll
                for (int r = 0; r < 4; ++r) {
                    int cls = 16 * mt + 4 * lq + r;
                    lg[(size_t)ls * 1024 + cls] = (cls < LL) ? (a[r] + bout[cls]) : -INFINITY;
                }
            }
            __syncthreads();
            const int s2 = tid >> 5;
            const int i2 = tid & 31;
            const float* row = &lg[(size_t)s2 * 1024];
            float mx = -INFINITY;
#pragma unroll
            for (int k = 0; k < 32; ++k) mx = fmaxf(mx, row[i2 + 32 * k]);
            mx = fmaxf(mx, __shfl_xor(mx, 1, 64));
            mx = fmaxf(mx, __shfl_xor(mx, 2, 64));
            mx = fmaxf(mx, __shfl_xor(mx, 4, 64));
            mx = fmaxf(mx, __shfl_xor(mx, 8, 64));
            mx = fmaxf(mx, __shfl_xor(mx, 16, 64));
            float sm = 0.0f;
#pragma unroll
            for (int k = 0; k < 32; ++k) sm += __expf(row[i2 + 32 * k] - mx);
            sm += __shfl_xor(sm, 1, 64);
            sm += __shfl_xor(sm, 2, 64);
            sm += __shfl_xor(sm, 4, 64);
            sm += __shfl_xor(sm, 8, 64);
            sm += __shfl_xor(sm, 16, 64);
            if (i2 == 0) {
                int lab = labv[cgo * 16 + s2];
                float lp = row[lab] - mx - __logf(sm);
                lossAcc += -lp;
            }
        }
        if ((tid & 31) == 0)
            atomicAdd(&out[HH], lossAcc * (1.0f / NSEQ));
    }
}

extern "C" void kernel_launch(void* const* d_in, const int* in_sizes, int n_in,
                              void* d_out, int out_size, void* d_ws, size_t ws_size,
                              hipStream_t stream)
{
    const int*   tokens  = (const int*)d_in[0];
    const int*   lengths = (const int*)d_in[1];
    const int*   labels  = (const int*)d_in[2];
    const float* emb     = (const float*)d_in[3];
    const float* Wih     = (const float*)d_in[4];
    const float* Whh     = (const float*)d_in[5];
    const float* bih     = (const float*)d_in[6];
    const float* bhh     = (const float*)d_in[7];
    const float* Wout    = (const float*)d_in[8];
    const float* bout    = (const float*)d_in[9];
    float* out = (float*)d_out;

    unsigned short* wsA  = (unsigned short*)d_ws;
    unsigned short* wsO  = wsA + WSA_ELEMS;
    unsigned short* ghf  = wsO + WSO_ELEMS;
    int*            flg  = (int*)(ghf + GHF_SHORTS);

    hipLaunchKernelGGL(init_out_kernel, dim3(8), dim3(512), 0, stream, out, flg);
    {
        int nthr = NMT * NKT * 64 + NMT * NKT_O * 64;
        hipLaunchKernelGGL(convert_weights, dim3((nthr + 255) / 256), dim3(256), 0, stream,
                           Wih, Whh, Wout, wsA, wsO);
    }
    hipLaunchKernelGGL(lstm_wave_kernel, dim3(NGRP * NMEM), dim3(NT), 0, stream,
                       tokens, lengths, labels, emb, bih, bhh, bout, wsA, wsO, ghf, flg, out);
}

// Round 10
// 1004.391 us; speedup vs baseline: 1.4360x; 1.4360x over previous
//
#include <hip/hip_runtime.h>
#include <hip/hip_bf16.h>
#include <math.h>

// Problem constants
#define NSEQ 2048
#define TT   128
#define EE   128
#define HH   256
#define GG   1024
#define LL   1000
#define NT   512        // 8 waves
#define NGRP 32         // groups of 64 seqs
#define NMEM 8          // members (blocks) per group; member owns 32 h-units
#define SEQG 64
#define NKT  12         // K-tiles of 32: 4 x + 8 h
#define NMT  64
#define NKT_O 8
#define WSA_ELEMS (NMT * NKT * 64 * 8)      // 768 KB bf16
#define WSO_ELEMS (NMT * NKT_O * 64 * 8)    // 512 KB bf16
// ghf: [grp][member][parity][cg][64 lanes][8 shorts] = 2 MB
#define GHF_SHORTS ((size_t)NGRP * NMEM * 2 * 4 * 64 * 8)
#define NTAGS (NGRP * 4 * 16)               // one 64B line (16 ints) per (grp,cg)

typedef __attribute__((ext_vector_type(8))) short bf16x8;
typedef __attribute__((ext_vector_type(4))) float f32x4;
typedef unsigned long long u64;

__device__ __forceinline__ unsigned short f2bf(float f) {
    union { float f; unsigned u; } v; v.f = f;
    unsigned r = v.u + 0x7FFF + ((v.u >> 16) & 1);   // RNE
    return (unsigned short)(r >> 16);
}
__device__ __forceinline__ float sigf(float x) { return 1.0f / (1.0f + __expf(-x)); }
__device__ __forceinline__ float tanh_fast(float x) { return 1.0f - 2.0f / (1.0f + __expf(2.0f * x)); }

// system-scope relaxed ops: sc0+sc1 (served at coherence point) — NO wbl2/inv
__device__ __forceinline__ void st8_sys(unsigned short* p, unsigned lo, unsigned hi) {
    u64 v = (u64)lo | ((u64)hi << 32);
    __hip_atomic_store((u64*)p, v, __ATOMIC_RELAXED, __HIP_MEMORY_SCOPE_SYSTEM);
}
__device__ __forceinline__ bf16x8 ld16_sys(const unsigned short* p) {
    u64 lo = __hip_atomic_load((const u64*)p,       __ATOMIC_RELAXED, __HIP_MEMORY_SCOPE_SYSTEM);
    u64 hi = __hip_atomic_load((const u64*)(p + 4), __ATOMIC_RELAXED, __HIP_MEMORY_SCOPE_SYSTEM);
    union { u64 q[2]; bf16x8 v; } u; u.q[0] = lo; u.q[1] = hi;
    return u.v;
}

// init: out zeros, all tags = 1 (h(0) available), ghf parity-0 data = 0.
// Plain stores: kernel-boundary writeback makes them visible to sc1 loads.
__global__ void init_all_kernel(float* out, int* tags, unsigned short* ghf) {
    int i = blockIdx.x * blockDim.x + threadIdx.x;   // 256*512 = 131072 threads
    if (i < HH + 1) out[i] = 0.0f;
    if (i < NTAGS) tags[i] = 1;
    // parity-0 slice of each (grp,member): first 2048 shorts of each 4096-short pair
    int gm = i >> 9, j = i & 511;                    // 256 members x 512 u64
    ((u64*)ghf)[(size_t)gm * 1024 + j] = 0ull;
}

// Pre-shuffle weights into MFMA A-fragment order, bf16 (layout verified R2-R9).
__global__ void convert_weights(const float* __restrict__ Wih, const float* __restrict__ Whh,
                                const float* __restrict__ Wout,
                                unsigned short* __restrict__ wsA, unsigned short* __restrict__ wsO) {
    int gid = blockIdx.x * blockDim.x + threadIdx.x;
    if (gid < NMT * NKT * 64) {
        int lane = gid & 63, tile = gid >> 6;
        int kt = tile % NKT, mt = tile / NKT;
        int row = mt * 16 + (lane & 15);
        int kb  = kt * 32 + (lane >> 4) * 8;
        unsigned short o[8];
#pragma unroll
        for (int j = 0; j < 8; ++j) {
            int k = kb + j;
            float v = (k < EE) ? Wih[row * EE + k] : Whh[row * HH + (k - EE)];
            o[j] = f2bf(v);
        }
        uint4 pk;
        pk.x = o[0] | ((unsigned)o[1] << 16); pk.y = o[2] | ((unsigned)o[3] << 16);
        pk.z = o[4] | ((unsigned)o[5] << 16); pk.w = o[6] | ((unsigned)o[7] << 16);
        *(uint4*)(wsA + (size_t)gid * 8) = pk;
    } else {
        int g2 = gid - NMT * NKT * 64;
        if (g2 < NMT * NKT_O * 64) {
            int lane = g2 & 63, tile = g2 >> 6;
            int kt = tile % NKT_O, mt = tile / NKT_O;
            int row = mt * 16 + (lane & 15);
            int ub  = kt * 32 + (lane >> 4) * 8;
            unsigned short o[8];
#pragma unroll
            for (int j = 0; j < 8; ++j)
                o[j] = (row < LL) ? f2bf(Wout[row * HH + ub + j]) : (unsigned short)0;
            uint4 pk;
            pk.x = o[0] | ((unsigned)o[1] << 16); pk.y = o[2] | ((unsigned)o[3] << 16);
            pk.z = o[4] | ((unsigned)o[5] << 16); pk.w = o[6] | ((unsigned)o[7] << 16);
            *(uint4*)(wsO + (size_t)g2 * 8) = pk;
        }
    }
}

// Barrier-free 8-way split LSTM. Sync: per-wave monotonic tags packed one 64B
// line per (grp,cg) cohort — coalesced single-load polling, no hotspot.
// Producer: data st8 -> wave s_waitcnt(0) -> tag st. Consumer: poll -> ld16.
__launch_bounds__(NT, 2)
__global__ void lstm_wave_kernel(
    const int* __restrict__ tokens, const int* __restrict__ lengths,
    const int* __restrict__ labels, const float* __restrict__ emb,
    const float* __restrict__ bih,  const float* __restrict__ bhh,
    const float* __restrict__ bout,
    const unsigned short* __restrict__ wsA, const unsigned short* __restrict__ wsO,
    unsigned short* __restrict__ ghf, int* __restrict__ tags,
    float* __restrict__ out)
{
    __shared__ __align__(16) unsigned short wlds[8 * 12 * 64 * 8];   // 96 KB A-frags
    __shared__ int labv[SEQG];

    const int tid = threadIdx.x;
    const int w   = tid >> 6;
    const int l   = tid & 63;
    const int lq  = l >> 4;
    const int ls  = l & 15;
    const int jj  = w >> 2;        // row half (0/1)
    const int cg  = w & 3;         // col group (16 seqs)
    const int grp = blockIdx.x & (NGRP - 1);
    const int m   = blockIdx.x >> 5;
    const int n0  = grp * SEQG;

    int* const tagLine = tags + (grp * 4 + cg) * 16;   // cohort's 64B tag line
    const int  myTag   = m * 2 + jj;                   // slot in the line

    int maxlen = lengths[n0 + l];
#pragma unroll
    for (int s = 1; s < 64; s <<= 1) maxlen = max(maxlen, __shfl_xor(maxlen, s, 64));
    const int len_s = lengths[n0 + cg * 16 + ls];
    const int myseq = n0 + cg * 16 + ls;

    if (tid < SEQG) labv[tid] = labels[n0 + tid];

    // biases in registers
    f32x4 biasv[4];
#pragma unroll
    for (int g = 0; g < 4; ++g)
#pragma unroll
        for (int r = 0; r < 4; ++r) {
            int row = 256 * g + 32 * m + 16 * jj + 4 * lq + r;
            biasv[g][r] = bih[row] + bhh[row];
        }

    // ---- one-time: this member's A-frags (8 mt x 12 kt) -> LDS ----
    for (int idx = tid; idx < 8 * 12 * 64; idx += NT) {
        int mtl = idx / 768;
        int rem = idx - mtl * 768;
        int kt = rem >> 6, l2 = rem & 63;
        int g = mtl >> 1, j2 = mtl & 1;
        int gmt = 16 * g + 2 * m + j2;
        *(uint4*)&wlds[(size_t)idx * 8] =
            *(const uint4*)(wsA + ((size_t)(gmt * NKT + kt) * 64 + l2) * 8);
    }

    // h publish mapping: unit u = 16*jj + 4*lq + r
    const int u8      = 2 * jj + (lq >> 1);
    const int lanep_h = 16 * u8 + ls;
    const int joff_h  = 4 * (lq & 1);
    const size_t gb0  = ((size_t)((grp * NMEM + m) * 2 + 0) * 4 + cg) * 512 + (size_t)lanep_h * 8 + joff_h;
    const size_t gb1  = gb0 + 4 * 512;

    // x gather: lane l -> emb[token(myseq,t)][kt*32 + (l>>4)*8 + j]
    const int xoff = (l >> 4) * 8;
    bf16x8 bx[4];
    {
        int tok = tokens[myseq * TT + 0];
        const float* er = emb + (size_t)tok * EE + xoff;
#pragma unroll
        for (int kt = 0; kt < 4; ++kt) {
            f32x4 a = *(const f32x4*)(er + kt * 32);
            f32x4 b = *(const f32x4*)(er + kt * 32 + 4);
            union { unsigned u[4]; bf16x8 v; } pk;
            pk.u[0] = f2bf(a[0]) | ((unsigned)f2bf(a[1]) << 16);
            pk.u[1] = f2bf(a[2]) | ((unsigned)f2bf(a[3]) << 16);
            pk.u[2] = f2bf(b[0]) | ((unsigned)f2bf(b[1]) << 16);
            pk.u[3] = f2bf(b[2]) | ((unsigned)f2bf(b[3]) << 16);
            bx[kt] = pk.v;
        }
    }

    __syncthreads();   // wlds + labv visible (only block barrier)

    // acc = bias + W_ih * x(0)
    f32x4 acc[4];
#pragma unroll
    for (int g = 0; g < 4; ++g) acc[g] = biasv[g];
#pragma unroll
    for (int kt = 0; kt < 4; ++kt)
#pragma unroll
        for (int g = 0; g < 4; ++g)
            acc[g] = __builtin_amdgcn_mfma_f32_16x16x32_bf16(
                *(const bf16x8*)&wlds[(size_t)(((2 * g + jj) * 12 + kt) * 64 + l) * 8],
                bx[kt], acc[g], 0, 0, 0);

    float c_reg[4], h_reg[4];
#pragma unroll
    for (int r = 0; r < 4; ++r) { c_reg[r] = 0.0f; h_reg[r] = 0.0f; }

    // per-wave wait: cohort tag line (16 tags, one coalesced load) >= need
    auto wave_wait = [&](int need) {
        int f;
        do {
            f = 0x7fffffff;
            if (l < 16)
                f = __hip_atomic_load(&tagLine[l], __ATOMIC_RELAXED, __HIP_MEMORY_SCOPE_SYSTEM);
            f = min(f, __shfl_xor(f, 1, 64));
            f = min(f, __shfl_xor(f, 2, 64));
            f = min(f, __shfl_xor(f, 4, 64));
            f = min(f, __shfl_xor(f, 8, 64));
            f = __shfl(f, 0, 64);
        } while (f < need);
        asm volatile("" ::: "memory");
    };

    // ---- recurrence: zero barriers, zero block-wide drains ----
    for (int t = 0; t < maxlen; ++t) {
        const int par = t & 1;

        // wait all 16 producer-waves' h(t) of this cg (tags init'd to 1)
        wave_wait(t + 1);

        // 8 member tiles as B-frags from L3
        bf16x8 bp[8];
#pragma unroll
        for (int p = 0; p < 8; ++p) {
            size_t b = ((size_t)((grp * NMEM + p) * 2 + par) * 4 + cg) * 512;
            bp[p] = ld16_sys(&ghf[b + (size_t)l * 8]);
        }
        // h-part MFMAs
#pragma unroll
        for (int p = 0; p < 8; ++p)
#pragma unroll
            for (int g = 0; g < 4; ++g)
                acc[g] = __builtin_amdgcn_mfma_f32_16x16x32_bf16(
                    *(const bf16x8*)&wlds[(size_t)(((2 * g + jj) * 12 + 4 + p) * 64 + l) * 8],
                    bp[p], acc[g], 0, 0, 0);

        // in-register cell update
        const bool live = (t < len_s);
#pragma unroll
        for (int r = 0; r < 4; ++r) {
            if (live) {
                float ig = sigf(acc[0][r]);
                float fg = sigf(acc[1][r]);
                float gg = tanh_fast(acc[2][r]);
                float og = sigf(acc[3][r]);
                float cc = fg * c_reg[r] + ig * gg;
                c_reg[r] = cc;
                h_reg[r] = og * tanh_fast(cc);
            }
        }

        // publish h(t+1): data st8 -> wave drain -> tag = t+2
        {
            uint2 hp;
            hp.x = f2bf(h_reg[0]) | ((unsigned)f2bf(h_reg[1]) << 16);
            hp.y = f2bf(h_reg[2]) | ((unsigned)f2bf(h_reg[3]) << 16);
            st8_sys(&ghf[par ? gb0 : gb1], hp.x, hp.y);
        }
        __builtin_amdgcn_s_waitcnt(0);
        asm volatile("" ::: "memory");
        if (l == 0)
            __hip_atomic_store(&tagLine[myTag], t + 2, __ATOMIC_RELAXED, __HIP_MEMORY_SCOPE_SYSTEM);

        // off critical path: gather x(t+1), pre-accumulate x-part
        if (t + 1 < maxlen) {
            int tok = tokens[myseq * TT + t + 1];
            const float* er = emb + (size_t)tok * EE + xoff;
#pragma unroll
            for (int kt = 0; kt < 4; ++kt) {
                f32x4 a = *(const f32x4*)(er + kt * 32);
                f32x4 b = *(const f32x4*)(er + kt * 32 + 4);
                union { unsigned u[4]; bf16x8 v; } pk;
                pk.u[0] = f2bf(a[0]) | ((unsigned)f2bf(a[1]) << 16);
                pk.u[1] = f2bf(a[2]) | ((unsigned)f2bf(a[3]) << 16);
                pk.u[2] = f2bf(b[0]) | ((unsigned)f2bf(b[1]) << 16);
                pk.u[3] = f2bf(b[2]) | ((unsigned)f2bf(b[3]) << 16);
                bx[kt] = pk.v;
            }
#pragma unroll
            for (int g = 0; g < 4; ++g) acc[g] = biasv[g];
#pragma unroll
            for (int kt = 0; kt < 4; ++kt)
#pragma unroll
                for (int g = 0; g < 4; ++g)
                    acc[g] = __builtin_amdgcn_mfma_f32_16x16x32_bf16(
                        *(const bf16x8*)&wlds[(size_t)(((2 * g + jj) * 12 + kt) * 64 + l) * 8],
                        bx[kt], acc[g], 0, 0, 0);
        }
    }

    // ---- epilogue 1: embeds = mean(c_f) for own 32 units ----
#pragma unroll
    for (int r = 0; r < 4; ++r) {
        float v = c_reg[r];
        v += __shfl_xor(v, 1, 64);
        v += __shfl_xor(v, 2, 64);
        v += __shfl_xor(v, 4, 64);
        v += __shfl_xor(v, 8, 64);
        if (ls == 0)
            atomicAdd(&out[32 * m + 16 * jj + 4 * lq + r], v * (1.0f / NSEQ));
    }

    // ---- epilogue 2 (member 0): logits GEMM + log-softmax ----
    if (m == 0) {
        // wait all 64 cohort tags (4 cg x 16) >= maxlen+1
        {
            int* tbase = tags + grp * 64;
            int f;
            do {
                f = __hip_atomic_load(&tbase[l], __ATOMIC_RELAXED, __HIP_MEMORY_SCOPE_SYSTEM);
                f = min(f, __shfl_xor(f, 1, 64));
                f = min(f, __shfl_xor(f, 2, 64));
                f = min(f, __shfl_xor(f, 4, 64));
                f = min(f, __shfl_xor(f, 8, 64));
                f = min(f, __shfl_xor(f, 16, 64));
                f = min(f, __shfl_xor(f, 32, 64));
            } while (f < maxlen + 1);
            asm volatile("" ::: "memory");
        }
        const int fin = maxlen & 1;
        float* lg = (float*)wlds;            // reuse: 16 seqs x 1024 logits (64 KB)
        float lossAcc = 0.0f;

        for (int cgo = 0; cgo < 4; ++cgo) {
            bf16x8 bq[8];
#pragma unroll
            for (int p = 0; p < 8; ++p) {
                size_t b = ((size_t)((grp * NMEM + p) * 2 + fin) * 4 + cgo) * 512;
                bq[p] = ld16_sys(&ghf[b + (size_t)l * 8]);
            }
            __syncthreads();   // prev cgo softmax reads / wlds reads done
#pragma unroll
            for (int i = 0; i < 8; ++i) {
                int mt = 8 * w + i;
                f32x4 a = {0.0f, 0.0f, 0.0f, 0.0f};
#pragma unroll
                for (int p = 0; p < 8; ++p)
                    a = __builtin_amdgcn_mfma_f32_16x16x32_bf16(
                        *(const bf16x8*)(wsO + ((size_t)(mt * NKT_O + p) * 64 + l) * 8),
                        bq[p], a, 0, 0, 0);
#pragma unroll
                for (int r = 0; r < 4; ++r) {
                    int cls = 16 * mt + 4 * lq + r;
                    lg[(size_t)ls * 1024 + cls] = (cls < LL) ? (a[r] + bout[cls]) : -INFINITY;
                }
            }
            __syncthreads();
            const int s2 = tid >> 5;
            const int i2 = tid & 31;
            const float* row = &lg[(size_t)s2 * 1024];
            float mx = -INFINITY;
#pragma unroll
            for (int k = 0; k < 32; ++k) mx = fmaxf(mx, row[i2 + 32 * k]);
            mx = fmaxf(mx, __shfl_xor(mx, 1, 64));
            mx = fmaxf(mx, __shfl_xor(mx, 2, 64));
            mx = fmaxf(mx, __shfl_xor(mx, 4, 64));
            mx = fmaxf(mx, __shfl_xor(mx, 8, 64));
            mx = fmaxf(mx, __shfl_xor(mx, 16, 64));
            float sm = 0.0f;
#pragma unroll
            for (int k = 0; k < 32; ++k) sm += __expf(row[i2 + 32 * k] - mx);
            sm += __shfl_xor(sm, 1, 64);
            sm += __shfl_xor(sm, 2, 64);
            sm += __shfl_xor(sm, 4, 64);
            sm += __shfl_xor(sm, 8, 64);
            sm += __shfl_xor(sm, 16, 64);
            if (i2 == 0) {
                int lab = labv[cgo * 16 + s2];
                float lp = row[lab] - mx - __logf(sm);
                lossAcc += -lp;
            }
        }
        if ((tid & 31) == 0)
            atomicAdd(&out[HH], lossAcc * (1.0f / NSEQ));
    }
}

extern "C" void kernel_launch(void* const* d_in, const int* in_sizes, int n_in,
                              void* d_out, int out_size, void* d_ws, size_t ws_size,
                              hipStream_t stream)
{
    const int*   tokens  = (const int*)d_in[0];
    const int*   lengths = (const int*)d_in[1];
    const int*   labels  = (const int*)d_in[2];
    const float* emb     = (const float*)d_in[3];
    const float* Wih     = (const float*)d_in[4];
    const float* Whh     = (const float*)d_in[5];
    const float* bih     = (const float*)d_in[6];
    const float* bhh     = (const float*)d_in[7];
    const float* Wout    = (const float*)d_in[8];
    const float* bout    = (const float*)d_in[9];
    float* out = (float*)d_out;

    unsigned short* wsA  = (unsigned short*)d_ws;
    unsigned short* wsO  = wsA + WSA_ELEMS;
    unsigned short* ghf  = wsO + WSO_ELEMS;
    int*            tg   = (int*)(ghf + GHF_SHORTS);   // 8 KB tags; ws ~3.3 MB

    hipLaunchKernelGGL(init_all_kernel, dim3(256), dim3(512), 0, stream, out, tg, ghf);
    {
        int nthr = NMT * NKT * 64 + NMT * NKT_O * 64;
        hipLaunchKernelGGL(convert_weights, dim3((nthr + 255) / 256), dim3(256), 0, stream,
                           Wih, Whh, Wout, wsA, wsO);
    }
    hipLaunchKernelGGL(lstm_wave_kernel, dim3(NGRP * NMEM), dim3(NT), 0, stream,
                       tokens, lengths, labels, emb, bih, bhh, bout, wsA, wsO, ghf, tg, out);
}

// Round 11
// 712.974 us; speedup vs baseline: 2.0229x; 1.4087x over previous
//
#include <hip/hip_runtime.h>
#include <hip/hip_bf16.h>
#include <math.h>

// Problem constants
#define NSEQ 2048
#define TT   128
#define EE   128
#define HH   256
#define GG   1024
#define LL   1000
#define NT   512        // 8 waves
#define NGRP 32         // groups of 64 seqs
#define NMEM 8          // members (blocks) per group; member owns 32 h-units
#define SEQG 64
#define NKT  12         // K-tiles of 32: 4 x + 8 h
#define NMT  64
#define NKT_O 8
#define WSA_ELEMS (NMT * NKT * 64 * 8)      // 768 KB bf16
#define WSO_ELEMS (NMT * NKT_O * 64 * 8)    // 512 KB bf16
// ghf: [grp][member][parity][cg][64 lanes][8 shorts] = 2 MB
#define GHF_SHORTS ((size_t)NGRP * NMEM * 2 * 4 * 64 * 8)

typedef __attribute__((ext_vector_type(8))) short bf16x8;
typedef __attribute__((ext_vector_type(4))) float f32x4;
typedef unsigned long long u64;

__device__ __forceinline__ unsigned short f2bf(float f) {
    union { float f; unsigned u; } v; v.f = f;
    unsigned r = v.u + 0x7FFF + ((v.u >> 16) & 1);   // RNE
    return (unsigned short)(r >> 16);
}
__device__ __forceinline__ float sigf(float x) { return 1.0f / (1.0f + __expf(-x)); }
__device__ __forceinline__ float tanh_fast(float x) { return 1.0f - 2.0f / (1.0f + __expf(2.0f * x)); }

// scope-templated relaxed ops. AGENT = sc0 only (XCD L2, ~250cy RT);
// SYSTEM = sc0+sc1 (MALL, ~700-900cy RT). Relaxed => no wbl2 / buffer_inv.
template<int S>
__device__ __forceinline__ void st8_s(unsigned short* p, unsigned lo, unsigned hi) {
    u64 v = (u64)lo | ((u64)hi << 32);
    __hip_atomic_store((u64*)p, v, __ATOMIC_RELAXED, S);
}
template<int S>
__device__ __forceinline__ bf16x8 ld16_s(const unsigned short* p) {
    u64 lo = __hip_atomic_load((const u64*)p,       __ATOMIC_RELAXED, S);
    u64 hi = __hip_atomic_load((const u64*)(p + 4), __ATOMIC_RELAXED, S);
    union { u64 q[2]; bf16x8 v; } u; u.q[0] = lo; u.q[1] = hi;
    return u.v;
}

__global__ void init_all_kernel(float* out, int* flags, int* xcds) {
    int i = blockIdx.x * blockDim.x + threadIdx.x;
    if (i < HH + 1) out[i] = 0.0f;
    if (i < NGRP * NMEM) { flags[i] = 0; xcds[i] = -1; }
}

// Pre-shuffle weights into MFMA A-fragment order, bf16 (layout verified R2-R10).
__global__ void convert_weights(const float* __restrict__ Wih, const float* __restrict__ Whh,
                                const float* __restrict__ Wout,
                                unsigned short* __restrict__ wsA, unsigned short* __restrict__ wsO) {
    int gid = blockIdx.x * blockDim.x + threadIdx.x;
    if (gid < NMT * NKT * 64) {
        int lane = gid & 63, tile = gid >> 6;
        int kt = tile % NKT, mt = tile / NKT;
        int row = mt * 16 + (lane & 15);
        int kb  = kt * 32 + (lane >> 4) * 8;
        unsigned short o[8];
#pragma unroll
        for (int j = 0; j < 8; ++j) {
            int k = kb + j;
            float v = (k < EE) ? Wih[row * EE + k] : Whh[row * HH + (k - EE)];
            o[j] = f2bf(v);
        }
        uint4 pk;
        pk.x = o[0] | ((unsigned)o[1] << 16); pk.y = o[2] | ((unsigned)o[3] << 16);
        pk.z = o[4] | ((unsigned)o[5] << 16); pk.w = o[6] | ((unsigned)o[7] << 16);
        *(uint4*)(wsA + (size_t)gid * 8) = pk;
    } else {
        int g2 = gid - NMT * NKT * 64;
        if (g2 < NMT * NKT_O * 64) {
            int lane = g2 & 63, tile = g2 >> 6;
            int kt = tile % NKT_O, mt = tile / NKT_O;
            int row = mt * 16 + (lane & 15);
            int ub  = kt * 32 + (lane >> 4) * 8;
            unsigned short o[8];
#pragma unroll
            for (int j = 0; j < 8; ++j)
                o[j] = (row < LL) ? f2bf(Wout[row * HH + ub + j]) : (unsigned short)0;
            uint4 pk;
            pk.x = o[0] | ((unsigned)o[1] << 16); pk.y = o[2] | ((unsigned)o[3] << 16);
            pk.z = o[4] | ((unsigned)o[5] << 16); pk.w = o[6] | ((unsigned)o[7] << 16);
            *(uint4*)(wsO + (size_t)g2 * 8) = pk;
        }
    }
}

// R8's verified body (barriers + wave0 relay + pipelined x-part), exchange
// scope-templated. Called with AGENT iff all 8 members verified co-XCD.
template<int S>
__device__ __forceinline__ void lstm_body(
    const int* __restrict__ tokens, const int* __restrict__ lengths,
    const int* __restrict__ labels, const float* __restrict__ emb,
    const float* __restrict__ bih,  const float* __restrict__ bhh,
    const float* __restrict__ bout,
    const unsigned short* __restrict__ wsA, const unsigned short* __restrict__ wsO,
    unsigned short* __restrict__ ghf, int* __restrict__ flags,
    float* __restrict__ out,
    unsigned short* wlds, unsigned short* xfS, unsigned short* hf,
    float (*redm)[16], float (*reds)[16], int* labv, int* ready_s)
{
    const int tid = threadIdx.x;
    const int w   = tid >> 6;
    const int l   = tid & 63;
    const int lq  = l >> 4;
    const int ls  = l & 15;
    const int jj  = w >> 2;        // row half (0/1)
    const int cg  = w & 3;         // col group (16 seqs)
    const int grp = blockIdx.x & (NGRP - 1);
    const int m   = blockIdx.x >> 5;
    const int n0  = grp * SEQG;

    int* const flagBase = flags + grp * NMEM;

    int maxlen = lengths[n0 + l];
#pragma unroll
    for (int s = 1; s < 64; s <<= 1) maxlen = max(maxlen, __shfl_xor(maxlen, s, 64));
    const int len_s = lengths[n0 + cg * 16 + ls];

    if (tid < SEQG) labv[tid] = labels[n0 + tid];
    if (tid == 0) *ready_s = 0;

    // biases in registers
    f32x4 biasv[4];
#pragma unroll
    for (int g = 0; g < 4; ++g)
#pragma unroll
        for (int r = 0; r < 4; ++r) {
            int row = 256 * g + 32 * m + 16 * jj + 4 * lq + r;
            biasv[g][r] = bih[row] + bhh[row];
        }

    // one-time: this member's A-frags (8 mt x 12 kt) -> LDS
    for (int idx = tid; idx < 8 * 12 * 64; idx += NT) {
        int mtl = idx / 768;
        int rem = idx - mtl * 768;
        int kt = rem >> 6, l2 = rem & 63;
        int g = mtl >> 1, j2 = mtl & 1;
        int gmt = 16 * g + 2 * m + j2;
        *(uint4*)&wlds[(size_t)idx * 8] =
            *(const uint4*)(wsA + ((size_t)(gmt * NKT + kt) * 64 + l2) * 8);
    }

    // zero hf buf0 + ghf parity0 slice (h(0) = 0)
    if (tid < 256) {
        uint4 z = {0, 0, 0, 0};
        *(uint4*)&hf[(size_t)tid * 8] = z;
        size_t base = ((size_t)((grp * NMEM + m) * 2 + 0) * 4) * 512 + (size_t)tid * 8;
        st8_s<S>(&ghf[base], 0, 0);
        st8_s<S>(&ghf[base + 4], 0, 0);
    }

    // x staging map: thread -> (seq, 16-dim octet)
    const int xs_s   = tid & 63;
    const int xs_oct = tid >> 6;

    auto stageX = [&](const f32x4* xv) {
#pragma unroll
        for (int dc = 0; dc < 4; ++dc) {
            int d0 = 16 * xs_oct + 4 * dc;
            int kt = d0 >> 5, cgs = xs_s >> 4;
            int lanep = (xs_s & 15) + 16 * ((d0 >> 3) & 3);
            uint2 pk;
            pk.x = f2bf(xv[dc][0]) | ((unsigned)f2bf(xv[dc][1]) << 16);
            pk.y = f2bf(xv[dc][2]) | ((unsigned)f2bf(xv[dc][3]) << 16);
            *(uint2*)&xfS[(size_t)((kt * 4 + cgs) * 64 + lanep) * 8 + (d0 & 4)] = pk;
        }
    };

    // stage x(0)
    {
        int tok = tokens[(n0 + xs_s) * TT + 0];
        const float* er = emb + (size_t)tok * EE + 16 * xs_oct;
        f32x4 x0[4];
#pragma unroll
        for (int dc = 0; dc < 4; ++dc) x0[dc] = *(const f32x4*)(er + 4 * dc);
        stageX(x0);
    }
    __syncthreads();   // drains ghf zero stores + x(0) staging + wlds
    if (tid == 0)
        __hip_atomic_store(&flagBase[m], 1, __ATOMIC_RELAXED, S);

    // prefetch x(1)
    f32x4 xv[4];
    if (maxlen > 1) {
        int tok = tokens[(n0 + xs_s) * TT + 1];
        const float* er = emb + (size_t)tok * EE + 16 * xs_oct;
#pragma unroll
        for (int dc = 0; dc < 4; ++dc) xv[dc] = *(const f32x4*)(er + 4 * dc);
    }

    // acc = bias + xpart(x(0))
    f32x4 acc[4], accN[4];
#pragma unroll
    for (int g = 0; g < 4; ++g) acc[g] = biasv[g];
#pragma unroll
    for (int kt = 0; kt < 4; ++kt) {
        const bf16x8 bx = *(const bf16x8*)&xfS[(size_t)((kt * 4 + cg) * 64 + l) * 8];
#pragma unroll
        for (int g = 0; g < 4; ++g)
            acc[g] = __builtin_amdgcn_mfma_f32_16x16x32_bf16(
                *(const bf16x8*)&wlds[(size_t)(((2 * g + jj) * 12 + kt) * 64 + l) * 8],
                bx, acc[g], 0, 0, 0);
    }
    __syncthreads();   // xfS reads done; iter 0 may restage

    // relay wait: wave0 polls flags at scope S; other waves spin on LDS
    auto relay_wait = [&](int need) {
        if (w == 0) {
            int f;
            do {
                f = 0x7fffffff;
                if (l < NMEM)
                    f = __hip_atomic_load(&flagBase[l], __ATOMIC_RELAXED, S);
                f = min(f, __shfl_xor(f, 1, 64));
                f = min(f, __shfl_xor(f, 2, 64));
                f = min(f, __shfl_xor(f, 4, 64));
                f = __shfl(f, 0, 64);
                if (f < need) __builtin_amdgcn_s_sleep(2);
            } while (f < need);
            __hip_atomic_store(ready_s, need, __ATOMIC_RELEASE, __HIP_MEMORY_SCOPE_WORKGROUP);
        } else {
            while (__hip_atomic_load(ready_s, __ATOMIC_ACQUIRE, __HIP_MEMORY_SCOPE_WORKGROUP) < need)
                __builtin_amdgcn_s_sleep(1);
        }
        asm volatile("" ::: "memory");
    };

    float c_reg[4], h_reg[4];
#pragma unroll
    for (int r = 0; r < 4; ++r) { c_reg[r] = 0.0f; h_reg[r] = 0.0f; }

    // h publish mapping: unit u = 16*jj + 4*lq + r in member's 32-k tile
    const int u8      = 2 * jj + (lq >> 1);
    const int lanep_h = 16 * u8 + ls;
    const int joff_h  = 4 * (lq & 1);
    const size_t gb0  = ((size_t)((grp * NMEM + m) * 2 + 0) * 4 + cg) * 512 + (size_t)lanep_h * 8 + joff_h;
    const size_t gb1  = gb0 + 4 * 512;

    // ---- recurrence (steady state: xpart(t) already in acc) ----
    for (int t = 0; t < maxlen; ++t) {
        const int cur = t & 1, nxt = cur ^ 1;
        const bool doX = (t + 1 < maxlen);

        // head: stage x(t+1) from regs (partner-independent)
        if (doX) stageX(xv);
        const bf16x8 bo = *(const bf16x8*)&hf[(size_t)((cur * 4 + cg) * 64 + l) * 8];
        if (doX) __syncthreads();   // staging visible; cheap

        // prefetch x(t+2) (drained at barrier B, a full iter away)
        if (t + 2 < maxlen) {
            int tok = tokens[(n0 + xs_s) * TT + t + 2];
            const float* er = emb + (size_t)tok * EE + 16 * xs_oct;
#pragma unroll
            for (int dc = 0; dc < 4; ++dc) xv[dc] = *(const f32x4*)(er + 4 * dc);
        }

        // xpart(t+1) into accN — fills the wait window
        if (doX) {
#pragma unroll
            for (int g = 0; g < 4; ++g) accN[g] = biasv[g];
#pragma unroll
            for (int kt = 0; kt < 4; ++kt) {
                const bf16x8 bx = *(const bf16x8*)&xfS[(size_t)((kt * 4 + cg) * 64 + l) * 8];
#pragma unroll
                for (int g = 0; g < 4; ++g)
                    accN[g] = __builtin_amdgcn_mfma_f32_16x16x32_bf16(
                        *(const bf16x8*)&wlds[(size_t)(((2 * g + jj) * 12 + kt) * 64 + l) * 8],
                        bx, accN[g], 0, 0, 0);
            }
        }

        // wait for all members' h(t)
        relay_wait(t + 1);

        // partner B-frag loads (L2 if agent path, else MALL)
        bf16x8 bp[7];
#pragma unroll
        for (int i = 0; i < 7; ++i) {
            int p = i + (i >= m ? 1 : 0);
            size_t b = ((size_t)((grp * NMEM + p) * 2 + cur) * 4 + cg) * 512;
            bp[i] = ld16_s<S>(&ghf[b + (size_t)l * 8]);
        }

        // own-h part first (hides partner-load latency)
#pragma unroll
        for (int g = 0; g < 4; ++g)
            acc[g] = __builtin_amdgcn_mfma_f32_16x16x32_bf16(
                *(const bf16x8*)&wlds[(size_t)(((2 * g + jj) * 12 + 4 + m) * 64 + l) * 8],
                bo, acc[g], 0, 0, 0);
        // partner-h parts
#pragma unroll
        for (int i = 0; i < 7; ++i) {
            int p = i + (i >= m ? 1 : 0);
            int kt = 4 + p;
#pragma unroll
            for (int g = 0; g < 4; ++g)
                acc[g] = __builtin_amdgcn_mfma_f32_16x16x32_bf16(
                    *(const bf16x8*)&wlds[(size_t)(((2 * g + jj) * 12 + kt) * 64 + l) * 8],
                    bp[i], acc[g], 0, 0, 0);
        }

        // in-register cell update
        const bool live = (t < len_s);
#pragma unroll
        for (int r = 0; r < 4; ++r) {
            if (live) {
                float ig = sigf(acc[0][r]);
                float fg = sigf(acc[1][r]);
                float gg = tanh_fast(acc[2][r]);
                float og = sigf(acc[3][r]);
                float cc = fg * c_reg[r] + ig * gg;
                c_reg[r] = cc;
                h_reg[r] = og * tanh_fast(cc);
            }
        }

        // carry pipelined xpart
        if (doX) {
#pragma unroll
            for (int g = 0; g < 4; ++g) acc[g] = accN[g];
        }

        // publish h(t+1): LDS nxt + ghf (scope S), parity (t+1)&1
        {
            uint2 hp;
            hp.x = f2bf(h_reg[0]) | ((unsigned)f2bf(h_reg[1]) << 16);
            hp.y = f2bf(h_reg[2]) | ((unsigned)f2bf(h_reg[3]) << 16);
            *(uint2*)&hf[(size_t)((nxt * 4 + cg) * 64 + lanep_h) * 8 + joff_h] = hp;
            st8_s<S>(&ghf[((t + 1) & 1) ? gb1 : gb0], hp.x, hp.y);
        }

        __syncthreads();   // barrier B: drains ghf stores (+ x prefetch loads)
        if (tid == 0)
            __hip_atomic_store(&flagBase[m], t + 2, __ATOMIC_RELAXED, S);
    }

    // ---- epilogue 1: embeds = mean(c_f) for own 32 units ----
#pragma unroll
    for (int r = 0; r < 4; ++r) {
        float v = c_reg[r];
        v += __shfl_xor(v, 1, 64);
        v += __shfl_xor(v, 2, 64);
        v += __shfl_xor(v, 4, 64);
        v += __shfl_xor(v, 8, 64);
        if (ls == 0)
            atomicAdd(&out[32 * m + 16 * jj + 4 * lq + r], v * (1.0f / NSEQ));
    }

    // ---- epilogue 2 (member 0): logits GEMM + log-softmax ----
    if (m == 0) {
        relay_wait(maxlen + 1);
        const int fin = maxlen & 1;
        float* lg = (float*)wlds;            // reuse: 16 seqs x 1024 logits
        float lossAcc = 0.0f;

        for (int cgo = 0; cgo < 4; ++cgo) {
            bf16x8 bq[8];
#pragma unroll
            for (int p = 0; p < 8; ++p) {
                size_t b = ((size_t)((grp * NMEM + p) * 2 + fin) * 4 + cgo) * 512;
                bq[p] = ld16_s<S>(&ghf[b + (size_t)l * 8]);
            }
            __syncthreads();
#pragma unroll
            for (int i = 0; i < 8; ++i) {
                int mt = 8 * w + i;
                f32x4 a = {0.0f, 0.0f, 0.0f, 0.0f};
#pragma unroll
                for (int p = 0; p < 8; ++p)
                    a = __builtin_amdgcn_mfma_f32_16x16x32_bf16(
                        *(const bf16x8*)(wsO + ((size_t)(mt * NKT_O + p) * 64 + l) * 8),
                        bq[p], a, 0, 0, 0);
#pragma unroll
                for (int r = 0; r < 4; ++r) {
                    int cls = 16 * mt + 4 * lq + r;
                    lg[(size_t)ls * 1024 + cls] = (cls < LL) ? (a[r] + bout[cls]) : -INFINITY;
                }
            }
            __syncthreads();
            const int s2 = tid >> 5;
            const int i2 = tid & 31;
            const float* row = &lg[(size_t)s2 * 1024];
            float mx = -INFINITY;
#pragma unroll
            for (int k = 0; k < 32; ++k) mx = fmaxf(mx, row[i2 + 32 * k]);
            mx = fmaxf(mx, __shfl_xor(mx, 1, 64));
            mx = fmaxf(mx, __shfl_xor(mx, 2, 64));
            mx = fmaxf(mx, __shfl_xor(mx, 4, 64));
            mx = fmaxf(mx, __shfl_xor(mx, 8, 64));
            mx = fmaxf(mx, __shfl_xor(mx, 16, 64));
            float sm = 0.0f;
#pragma unroll
            for (int k = 0; k < 32; ++k) sm += __expf(row[i2 + 32 * k] - mx);
            sm += __shfl_xor(sm, 1, 64);
            sm += __shfl_xor(sm, 2, 64);
            sm += __shfl_xor(sm, 4, 64);
            sm += __shfl_xor(sm, 8, 64);
            sm += __shfl_xor(sm, 16, 64);
            if (i2 == 0) {
                int lab = labv[cgo * 16 + s2];
                float lp = row[lab] - mx - __logf(sm);
                lossAcc += -lp;
            }
        }
        if ((tid & 31) == 0)
            atomicAdd(&out[HH], lossAcc * (1.0f / NSEQ));
    }
}

__launch_bounds__(NT, 2)
__global__ void lstm_group_kernel(
    const int* __restrict__ tokens, const int* __restrict__ lengths,
    const int* __restrict__ labels, const float* __restrict__ emb,
    const float* __restrict__ bih,  const float* __restrict__ bhh,
    const float* __restrict__ bout,
    const unsigned short* __restrict__ wsA, const unsigned short* __restrict__ wsO,
    unsigned short* __restrict__ ghf, int* __restrict__ flags, int* __restrict__ xcds,
    float* __restrict__ out)
{
    __shared__ __align__(16) unsigned short wlds[8 * 12 * 64 * 8];   // 96 KB A-frags
    __shared__ __align__(16) unsigned short xfS[4 * 4 * 64 * 8];     // 16 KB x B-frags
    __shared__ __align__(16) unsigned short hf[2 * 4 * 64 * 8];      // 8 KB own-h (dbuf)
    __shared__ float redm[8][16];
    __shared__ float reds[8][16];
    __shared__ int   labv[SEQG];
    __shared__ int   ready_s;

    const int grp = blockIdx.x & (NGRP - 1);
    const int m   = blockIdx.x >> 5;
    const int l   = threadIdx.x & 63;

    // read this CU's XCC id (HW_REG_XCC_ID = id 20, offset 0, size 32)
    unsigned myxcd = __builtin_amdgcn_s_getreg((31 << 11) | (0 << 6) | 20) & 0xff;
    int* xbase = xcds + grp * NMEM;
    if (threadIdx.x == 0)
        __hip_atomic_store(&xbase[m], (int)myxcd, __ATOMIC_RELAXED, __HIP_MEMORY_SCOPE_SYSTEM);

    // every wave polls until all 8 members reported; compute uniformity
    int mn, mx;
    do {
        int f = 0x7fffffff, g = -0x7fffffff;
        if (l < NMEM) {
            int v = __hip_atomic_load(&xbase[l], __ATOMIC_RELAXED, __HIP_MEMORY_SCOPE_SYSTEM);
            f = v; g = v;
        }
#pragma unroll
        for (int s = 1; s < 8; s <<= 1) {
            f = min(f, __shfl_xor(f, s, 64));
            g = max(g, __shfl_xor(g, s, 64));
        }
        mn = __shfl(f, 0, 64);
        mx = __shfl(g, 0, 64);
        if (mn < 0) __builtin_amdgcn_s_sleep(1);
    } while (mn < 0);
    const bool uniform = (mn == mx);

    if (uniform)
        lstm_body<__HIP_MEMORY_SCOPE_AGENT>(tokens, lengths, labels, emb, bih, bhh, bout,
                                            wsA, wsO, ghf, flags, out,
                                            wlds, xfS, hf, redm, reds, labv, &ready_s);
    else
        lstm_body<__HIP_MEMORY_SCOPE_SYSTEM>(tokens, lengths, labels, emb, bih, bhh, bout,
                                             wsA, wsO, ghf, flags, out,
                                             wlds, xfS, hf, redm, reds, labv, &ready_s);
}

extern "C" void kernel_launch(void* const* d_in, const int* in_sizes, int n_in,
                              void* d_out, int out_size, void* d_ws, size_t ws_size,
                              hipStream_t stream)
{
    const int*   tokens  = (const int*)d_in[0];
    const int*   lengths = (const int*)d_in[1];
    const int*   labels  = (const int*)d_in[2];
    const float* emb     = (const float*)d_in[3];
    const float* Wih     = (const float*)d_in[4];
    const float* Whh     = (const float*)d_in[5];
    const float* bih     = (const float*)d_in[6];
    const float* bhh     = (const float*)d_in[7];
    const float* Wout    = (const float*)d_in[8];
    const float* bout    = (const float*)d_in[9];
    float* out = (float*)d_out;

    unsigned short* wsA  = (unsigned short*)d_ws;
    unsigned short* wsO  = wsA + WSA_ELEMS;
    unsigned short* ghf  = wsO + WSO_ELEMS;
    int*            flg  = (int*)(ghf + GHF_SHORTS);       // 256 ints
    int*            xcd  = flg + NGRP * NMEM;              // 256 ints; ws ~3.3 MB

    hipLaunchKernelGGL(init_all_kernel, dim3(1), dim3(512), 0, stream, out, flg, xcd);
    {
        int nthr = NMT * NKT * 64 + NMT * NKT_O * 64;
        hipLaunchKernelGGL(convert_weights, dim3((nthr + 255) / 256), dim3(256), 0, stream,
                           Wih, Whh, Wout, wsA, wsO);
    }
    hipLaunchKernelGGL(lstm_group_kernel, dim3(NGRP * NMEM), dim3(NT), 0, stream,
                       tokens, lengths, labels, emb, bih, bhh, bout, wsA, wsO, ghf, flg, xcd, out);
}